// Round 3
// baseline (395.943 us; speedup 1.0000x reference)
//
#include <hip/hip_runtime.h>

#define BATCH 4096
#define NNEG  200
#define NITEM 201   // pos + 200 neg
#define DIM   64
#define NPART 4
#define NCENT 256
#define CDIM  16

// Fused kernel: one block per user b (grid=4096, block=256 = 4 waves).
// Phase 1 (encode): wave w handles partition w. Each lane loads 4 centroid
//   rows (k = j*64+lane, 64B each, L2-hot: whole centroid table is 256 KB)
//   straight into registers, scores them against the user sub-embedding plus
//   gumbel noise, then a 64-lane butterfly argmax picks the winner
//   (first-index tie-break, matching jnp.argmax). Winning row -> uvs[] in LDS.
// Phase 2 (score): 16 lanes per item row; lane (tid&15) loads float4
//   #(tid&15) of the 256B row -> one load instruction covers four full rows,
//   line-aligned. 4-step shfl_xor reduce, results staged in LDS, coalesced
//   final store.
__global__ __launch_bounds__(256) void qvae_fused_kernel(
    const int*   __restrict__ user_id,
    const int*   __restrict__ pos_id,
    const int*   __restrict__ neg_ids,
    const float* __restrict__ user_table,
    const float* __restrict__ centroids,   // [NPART][NCENT][CDIM]
    const float* __restrict__ item_table,
    const float* __restrict__ gumbel_u,    // [NPART][BATCH][NCENT]
    float*       __restrict__ out)         // [BATCH] pos then [BATCH][NNEG] neg
{
    __shared__ float uvs[DIM];
    __shared__ int   ids[NITEM];
    __shared__ float res[NITEM];

    const int b    = blockIdx.x;
    const int tid  = threadIdx.x;
    const int w    = tid >> 6;    // wave index == partition index
    const int lane = tid & 63;

    // ---- Phase 1: vector-quantize partition w of user b ----
    const int uid = user_id[b];

    // 16-float user sub-embedding; wave-uniform addresses -> one line, broadcast.
    const float4* up4 = (const float4*)(user_table + (size_t)uid * DIM + w * CDIM);
    float ue[CDIM];
    #pragma unroll
    for (int i = 0; i < 4; ++i) {
        float4 v = up4[i];
        ue[4*i+0] = v.x; ue[4*i+1] = v.y; ue[4*i+2] = v.z; ue[4*i+3] = v.w;
    }
    float ue2 = 0.f;
    #pragma unroll
    for (int c = 0; c < CDIM; ++c) ue2 += ue[c] * ue[c];

    const float*  gp  = gumbel_u + ((size_t)w * BATCH + b) * NCENT;
    const float4* cb4 = (const float4*)(centroids + (size_t)w * NCENT * CDIM);

    float best_s = -INFINITY;
    int   best_k = 0;
    #pragma unroll
    for (int j = 0; j < 4; ++j) {
        const int k = j * 64 + lane;
        // Centroid row k into registers: lanes read consecutive 64B rows in
        // 16B chunks -> the 4 loads jointly cover each line exactly once.
        float cr[CDIM];
        #pragma unroll
        for (int i = 0; i < 4; ++i) {
            float4 v = cb4[k * 4 + i];
            cr[4*i+0] = v.x; cr[4*i+1] = v.y; cr[4*i+2] = v.z; cr[4*i+3] = v.w;
        }
        float c2 = 0.f, dot = 0.f;
        #pragma unroll
        for (int c = 0; c < CDIM; ++c) { c2 += cr[c] * cr[c]; dot += ue[c] * cr[c]; }
        const float u = gp[k];                 // coalesced across lanes
        const float g = -logf(-logf(u));       // gumbel noise
        const float s = -((ue2 + c2) - 2.0f * dot) + g;
        if (s > best_s) { best_s = s; best_k = k; }   // strict > keeps smallest k
    }

    // 64-lane butterfly argmax; tie -> smaller k (matches jnp.argmax).
    #pragma unroll
    for (int m = 1; m < 64; m <<= 1) {
        float so = __shfl_xor(best_s, m, 64);
        int   ko = __shfl_xor(best_k, m, 64);
        if (so > best_s || (so == best_s && ko < best_k)) { best_s = so; best_k = ko; }
    }

    // Winning centroid row becomes the quantized user sub-vector (64B read, L2).
    if (lane < CDIM) {
        uvs[w * CDIM + lane] = centroids[((size_t)w * NCENT + best_k) * CDIM + lane];
    }

    // Stage item ids while phase 1 finishes (independent, coalesced).
    if (tid == 0)         ids[0]   = pos_id[b];
    else if (tid <= NNEG) ids[tid] = neg_ids[(size_t)b * NNEG + tid - 1];
    __syncthreads();

    // ---- Phase 2: pos/neg scores ----
    const int grp = tid >> 4;   // 16 clusters of 16 lanes
    const int l16 = tid & 15;
    const float4 u4 = ((const float4*)uvs)[l16];

    for (int item = grp; item < NITEM; item += 16) {
        const float4 v = ((const float4*)(item_table + (size_t)ids[item] * DIM))[l16];
        float s = v.x * u4.x + v.y * u4.y + v.z * u4.z + v.w * u4.w;
        s += __shfl_xor(s, 1, 64);
        s += __shfl_xor(s, 2, 64);
        s += __shfl_xor(s, 4, 64);
        s += __shfl_xor(s, 8, 64);
        if (l16 == 0) res[item] = s;
    }
    __syncthreads();

    if (tid == 0)   out[b] = res[0];
    if (tid < NNEG) out[BATCH + (size_t)b * NNEG + tid] = res[tid + 1];
}

extern "C" void kernel_launch(void* const* d_in, const int* in_sizes, int n_in,
                              void* d_out, int out_size, void* d_ws, size_t ws_size,
                              hipStream_t stream) {
    const int*   user_id    = (const int*)  d_in[0];
    const int*   pos_id     = (const int*)  d_in[1];
    const int*   neg_ids    = (const int*)  d_in[2];
    const float* user_table = (const float*)d_in[3];
    const float* centroids  = (const float*)d_in[4];
    const float* item_table = (const float*)d_in[5];
    const float* gumbel_u   = (const float*)d_in[6];
    float* out = (float*)d_out;

    qvae_fused_kernel<<<BATCH, 256, 0, stream>>>(
        user_id, pos_id, neg_ids, user_table, centroids, item_table, gumbel_u, out);
}

// Round 4
// 349.856 us; speedup vs baseline: 1.1317x; 1.1317x over previous
//
#include <hip/hip_runtime.h>

#define BATCH 4096
#define NNEG  200
#define NITEM 201   // pos + 200 neg
#define DIM   64
#define NPART 4
#define NCENT 256
#define CDIM  16
#define CPAD  17   // 16 values + 1 slot for the row norm; odd stride kills LDS bank conflicts
#define USERS_PER_BLOCK 16

// Kernel 1: vector-quantize user embeddings.
// grid = (BATCH/16, NPART), block = 256 (4 waves). The block stages its
// partition's 16 KB centroid slice + row norms in LDS ONCE, then wave w
// processes users b0 + it*4 + w for it = 0..3 (amortizes staging 4x vs the
// R2 version). Per user: each lane scores 4 centroids (k = j*64 + lane),
// then a 64-lane butterfly argmax picks the winner (first-index tie-break,
// matching jnp.argmax). LDS row reads have stride 17 -> 2-way bank aliasing
// only (free per m136).
__global__ __launch_bounds__(256) void qvae_encode_kernel(
    const int*   __restrict__ user_id,
    const float* __restrict__ user_table,
    const float* __restrict__ centroids,   // [NPART][NCENT][CDIM]
    const float* __restrict__ gumbel_u,    // [NPART][BATCH][NCENT]
    float*       __restrict__ user_vec)    // [BATCH][DIM]
{
    __shared__ float cent[NCENT * CPAD];

    const int p    = blockIdx.y;
    const int tid  = threadIdx.x;
    const int w    = tid >> 6;
    const int lane = tid & 63;

    // Stage this partition's centroids into LDS (coalesced global reads).
    const float* cp = centroids + (size_t)p * NCENT * CDIM;
    for (int idx = tid; idx < NCENT * CDIM; idx += 256) {
        int row = idx >> 4, col = idx & 15;
        cent[row * CPAD + col] = cp[idx];
    }
    __syncthreads();
    // Each thread computes one row norm into the pad slot.
    {
        float s = 0.f;
        #pragma unroll
        for (int c = 0; c < CDIM; ++c) { float v = cent[tid * CPAD + c]; s += v * v; }
        cent[tid * CPAD + CDIM] = s;
    }
    __syncthreads();

    for (int it = 0; it < USERS_PER_BLOCK / 4; ++it) {
        const int b = blockIdx.x * USERS_PER_BLOCK + it * 4 + w;

        // This (b,p)'s 16-float user sub-embedding (wave-uniform row; broadcast).
        const int uid = user_id[b];
        const float* up = user_table + (size_t)uid * DIM + p * CDIM;
        float ue[CDIM];
        #pragma unroll
        for (int i = 0; i < 4; ++i) {
            float4 v = ((const float4*)up)[i];
            ue[4*i+0] = v.x; ue[4*i+1] = v.y; ue[4*i+2] = v.z; ue[4*i+3] = v.w;
        }
        float ue2 = 0.f;
        #pragma unroll
        for (int c = 0; c < CDIM; ++c) ue2 += ue[c] * ue[c];

        // Score 4 centroids per lane; gumbel loads are coalesced across lanes.
        const float* gp = gumbel_u + ((size_t)p * BATCH + b) * NCENT;
        float best_s = -INFINITY;
        int   best_k = 0;
        #pragma unroll
        for (int j = 0; j < 4; ++j) {
            const int k = j * 64 + lane;
            float u = gp[k];
            float g = -logf(-logf(u));           // gumbel noise
            float dot = 0.f, c2 = cent[k * CPAD + CDIM];
            #pragma unroll
            for (int c = 0; c < CDIM; ++c) dot += ue[c] * cent[k * CPAD + c];
            float dist = (ue2 + c2) - 2.0f * dot;
            float s = -dist + g;
            if (s > best_s) { best_s = s; best_k = k; }   // strict > keeps smallest k
        }

        // 64-lane butterfly argmax; tie -> smaller k (matches jnp.argmax).
        #pragma unroll
        for (int m = 1; m < 64; m <<= 1) {
            float so = __shfl_xor(best_s, m, 64);
            int   ko = __shfl_xor(best_k, m, 64);
            if (so > best_s || (so == best_s && ko < best_k)) { best_s = so; best_k = ko; }
        }

        // Winning centroid row becomes the quantized user sub-vector.
        if (lane < CDIM) {
            user_vec[(size_t)b * DIM + p * CDIM + lane] = cent[best_k * CPAD + lane];
        }
    }
}

// Kernel 2: pos/neg scores, coalesced gather (identical to the 357 us R2
// version). One block per user b. 16 lanes cooperate on one item row: lane
// (tid&15) loads float4 #(tid&15) of the 256B row -> one load instruction
// covers four full rows, line-aligned. 4-step shfl_xor reduces within the
// 16-lane cluster. Ids staged in LDS (coalesced), results staged in LDS for
// a fully coalesced final store.
__global__ __launch_bounds__(256) void qvae_score_kernel(
    const int*   __restrict__ pos_id,
    const int*   __restrict__ neg_ids,
    const float* __restrict__ item_table,
    const float* __restrict__ user_vec,
    float*       __restrict__ out)   // [BATCH] pos then [BATCH][NNEG] neg
{
    __shared__ float4 uv4[DIM / 4];
    __shared__ int    ids[NITEM];
    __shared__ float  res[NITEM];

    const int b   = blockIdx.x;
    const int tid = threadIdx.x;

    if (tid < DIM / 4) uv4[tid] = ((const float4*)(user_vec + (size_t)b * DIM))[tid];
    if (tid == 0)           ids[0]   = pos_id[b];
    else if (tid <= NNEG)   ids[tid] = neg_ids[(size_t)b * NNEG + tid - 1];
    __syncthreads();

    const int grp = tid >> 4;   // 16 clusters of 16 lanes
    const int l16 = tid & 15;
    const float4 u = uv4[l16];  // one-time LDS read, 2-way aliasing (free)

    for (int item = grp; item < NITEM; item += 16) {
        const float4 v = ((const float4*)(item_table + (size_t)ids[item] * DIM))[l16];
        float s = v.x * u.x + v.y * u.y + v.z * u.z + v.w * u.w;
        s += __shfl_xor(s, 1, 64);
        s += __shfl_xor(s, 2, 64);
        s += __shfl_xor(s, 4, 64);
        s += __shfl_xor(s, 8, 64);
        if (l16 == 0) res[item] = s;
    }
    __syncthreads();

    if (tid == 0)   out[b] = res[0];
    if (tid < NNEG) out[BATCH + (size_t)b * NNEG + tid] = res[tid + 1];
}

extern "C" void kernel_launch(void* const* d_in, const int* in_sizes, int n_in,
                              void* d_out, int out_size, void* d_ws, size_t ws_size,
                              hipStream_t stream) {
    const int*   user_id    = (const int*)  d_in[0];
    const int*   pos_id     = (const int*)  d_in[1];
    const int*   neg_ids    = (const int*)  d_in[2];
    const float* user_table = (const float*)d_in[3];
    const float* centroids  = (const float*)d_in[4];
    const float* item_table = (const float*)d_in[5];
    const float* gumbel_u   = (const float*)d_in[6];
    float* out = (float*)d_out;
    float* uv  = (float*)d_ws;   // BATCH*DIM floats = 1 MB scratch

    qvae_encode_kernel<<<dim3(BATCH / USERS_PER_BLOCK, NPART), 256, 0, stream>>>(
        user_id, user_table, centroids, gumbel_u, uv);
    qvae_score_kernel<<<BATCH, 256, 0, stream>>>(
        pos_id, neg_ids, item_table, uv, out);
}